// Round 1
// baseline (151.992 us; speedup 1.0000x reference)
//
#include <hip/hip_runtime.h>

// Fused 10-iteration screened-Laplace Jacobi solver, 2048^2 f32.
// One kernel: stage inputs -> LDS-resident double-buffered Jacobi with
// halo=10 trapezoid -> clamp epilogue written straight from registers.
// Iteration folded to V_new = nsum(V)*R + B with
//   R = mask ? 0 : 1/(4+relu(C)),  B = mask ? bc : 0
// so Dirichlet injection is free (FMA form, branchless).

#define RES    2048
#define HALO   10
#define DIMX   128
#define DIMY   56
#define OUTX   (DIMX - 2*HALO)   // 108
#define OUTY   (DIMY - 2*HALO)   // 36
#define NBX    ((RES + OUTX - 1) / OUTX)   // 19
#define NBY    ((RES + OUTY - 1) / OUTY)   // 57
#define NITER  10

__global__ __launch_bounds__(256, 2)
void laplace10_fused(const float* __restrict__ Xin,
                     const float* __restrict__ Cin,
                     const int*   __restrict__ BT,
                     const float* __restrict__ BCin,
                     float* __restrict__ OUT,
                     float* __restrict__ CPOS) {
  __shared__ __align__(16) float buf[2][DIMY][DIMX];  // 57.3 KB -> 2 blocks/CU
  float* const s0 = &buf[0][0][0];
  float* const s1 = &buf[1][0][0];

  const int t   = threadIdx.x;
  const int q   = t & 31;    // column quad 0..31  (lane-contiguous -> LDS conflict-free b128)
  const int ty  = t >> 5;    // row group 0..7, 7 rows each
  const int x0  = q * 4;
  const int y0  = ty * 7;
  const int tx0 = (int)blockIdx.x * OUTX - HALO;
  const int ty0 = (int)blockIdx.y * OUTY - HALO;
  const int gx0 = tx0 + x0;

  const bool xedge = (tx0 < 0) || (tx0 + DIMX > RES);

  // coalesced float2 staging (tx0 is always even -> 8B aligned)
  auto stage = [&](const float* __restrict__ g, float* __restrict__ sb) {
    if (!xedge) {
#pragma unroll
      for (int i = 0; i < 14; ++i) {
        const int idx = t + i * 256;
        const int y   = idx >> 6;
        const int xx  = (idx & 63) * 2;
        int gy = ty0 + y;
        gy = gy < 0 ? 0 : (gy > RES - 1 ? RES - 1 : gy);
        *(float2*)(sb + y * DIMX + xx) =
            *(const float2*)(g + (size_t)gy * RES + (tx0 + xx));
      }
    } else {
#pragma unroll
      for (int i = 0; i < 14; ++i) {
        const int idx = t + i * 256;
        const int y   = idx >> 6;
        const int xx  = (idx & 63) * 2;
        int gy = ty0 + y;
        gy = gy < 0 ? 0 : (gy > RES - 1 ? RES - 1 : gy);
        int ga = tx0 + xx, gb = tx0 + xx + 1;
        ga = ga < 0 ? 0 : (ga > RES - 1 ? RES - 1 : ga);
        gb = gb < 0 ? 0 : (gb > RES - 1 ? RES - 1 : gb);
        float2 v;
        v.x = g[(size_t)gy * RES + ga];
        v.y = g[(size_t)gy * RES + gb];
        *(float2*)(sb + y * DIMX + xx) = v;
      }
    }
  };

  // output-region predicates (per-thread constants)
  const bool in0 = (x0 + 0 >= HALO) && (x0 + 0 < HALO + OUTX);
  const bool in1 = (x0 + 1 >= HALO) && (x0 + 1 < HALO + OUTX);
  const bool in2 = (x0 + 2 >= HALO) && (x0 + 2 < HALO + OUTX);
  const bool in3 = (x0 + 3 >= HALO) && (x0 + 3 < HALO + OUTX);
  const bool fullq = in0 && in3 && (gx0 + 4 <= RES);

  // ---- 1. boundary_types -> mask bits ----
  stage((const float*)BT, s1);
  __syncthreads();
  unsigned mb = 0u;
#pragma unroll
  for (int i = 0; i < 7; ++i) {
    const float4 mv = *(const float4*)(s1 + (y0 + i) * DIMX + x0);
    if (__float_as_uint(mv.x) != 0u) mb |= 1u << (i * 4 + 0);
    if (__float_as_uint(mv.y) != 0u) mb |= 1u << (i * 4 + 1);
    if (__float_as_uint(mv.z) != 0u) mb |= 1u << (i * 4 + 2);
    if (__float_as_uint(mv.w) != 0u) mb |= 1u << (i * 4 + 3);
  }
  __syncthreads();

  // ---- 2. boundary_conditions -> B ----
  stage(BCin, s1);
  __syncthreads();
  float4 Bq[7];
#pragma unroll
  for (int i = 0; i < 7; ++i) {
    const float4 b = *(const float4*)(s1 + (y0 + i) * DIMX + x0);
    Bq[i].x = (mb >> (i * 4 + 0) & 1u) ? b.x : 0.0f;
    Bq[i].y = (mb >> (i * 4 + 1) & 1u) ? b.y : 0.0f;
    Bq[i].z = (mb >> (i * 4 + 2) & 1u) ? b.z : 0.0f;
    Bq[i].w = (mb >> (i * 4 + 3) & 1u) ? b.w : 0.0f;
  }
  __syncthreads();

  // ---- 3. C -> R, and write C_pos for owned output cells ----
  stage(Cin, s1);
  __syncthreads();
  float4 Rq[7];
#pragma unroll
  for (int i = 0; i < 7; ++i) {
    const int y = y0 + i;
    const float4 c = *(const float4*)(s1 + y * DIMX + x0);
    float4 cp;
    cp.x = c.x > 0.0f ? c.x : 0.0f;
    cp.y = c.y > 0.0f ? c.y : 0.0f;
    cp.z = c.z > 0.0f ? c.z : 0.0f;
    cp.w = c.w > 0.0f ? c.w : 0.0f;
    Rq[i].x = (mb >> (i * 4 + 0) & 1u) ? 0.0f : 1.0f / (4.0f + cp.x);
    Rq[i].y = (mb >> (i * 4 + 1) & 1u) ? 0.0f : 1.0f / (4.0f + cp.y);
    Rq[i].z = (mb >> (i * 4 + 2) & 1u) ? 0.0f : 1.0f / (4.0f + cp.z);
    Rq[i].w = (mb >> (i * 4 + 3) & 1u) ? 0.0f : 1.0f / (4.0f + cp.w);
    const int gy = ty0 + y;
    if (y >= HALO && y < HALO + OUTY && gy < RES) {
      const size_t ro = (size_t)gy * RES;
      if (fullq) {
        *(float2*)(CPOS + ro + gx0)     = make_float2(cp.x, cp.y);
        *(float2*)(CPOS + ro + gx0 + 2) = make_float2(cp.z, cp.w);
      } else {
        if (in0 && gx0 + 0 < RES) CPOS[ro + gx0 + 0] = cp.x;
        if (in1 && gx0 + 1 < RES) CPOS[ro + gx0 + 1] = cp.y;
        if (in2 && gx0 + 2 < RES) CPOS[ro + gx0 + 2] = cp.z;
        if (in3 && gx0 + 3 < RES) CPOS[ro + gx0 + 3] = cp.w;
      }
    }
  }
  __syncthreads();

  // ---- 4. x -> V0 into s0 ----
  stage(Xin, s1);
  __syncthreads();
#pragma unroll
  for (int i = 0; i < 7; ++i) {
    const float4 xv = *(const float4*)(s1 + (y0 + i) * DIMX + x0);
    float4 v0;
    v0.x = (mb >> (i * 4 + 0) & 1u) ? Bq[i].x : xv.x;
    v0.y = (mb >> (i * 4 + 1) & 1u) ? Bq[i].y : xv.y;
    v0.z = (mb >> (i * 4 + 2) & 1u) ? Bq[i].z : xv.z;
    v0.w = (mb >> (i * 4 + 3) & 1u) ? Bq[i].w : xv.w;
    *(float4*)(s0 + (y0 + i) * DIMX + x0) = v0;
  }
  __syncthreads();

  // per-thread constant neighbor plumbing
  const int xm = (x0 == 0) ? 0 : x0 - 1;                 // LDS-safe; value unused when lq0
  const int xp = (x0 + 4 >= DIMX) ? DIMX - 1 : x0 + 4;   // LDS-safe; value unused when rq3
  const bool lq0 = (gx0 + 0 <= 0);         // replicate-pad: left neighbor = self
  const bool lq1 = (gx0 + 1 <= 0);
  const bool lq2 = (gx0 + 2 <= 0);
  const bool lq3 = (gx0 + 3 <= 0);
  const bool rq0 = (gx0 + 0 >= RES - 1);
  const bool rq1 = (gx0 + 1 >= RES - 1);
  const bool rq2 = (gx0 + 2 >= RES - 1);
  const bool rq3 = (gx0 + 3 >= RES - 1);

  // ---- 10 Jacobi iterations, LDS double-buffered, shrinking trapezoid ----
#pragma unroll
  for (int it = 1; it <= NITER; ++it) {
    const float* const src = (it & 1) ? s0 : s1;
    float* const dst       = (it & 1) ? s1 : s0;
    float4 v[9];
#pragma unroll
    for (int j = 0; j < 9; ++j) {
      int r = y0 - 1 + j;
      r = r < 0 ? 0 : (r > DIMY - 1 ? DIMY - 1 : r);
      v[j] = *(const float4*)(src + r * DIMX + x0);
    }
#pragma unroll
    for (int i = 0; i < 7; ++i) {
      const int y = y0 + i;
      if (y < it || y >= DIMY - it) continue;  // trapezoid: rim invalid beyond distance it
      const int gy = ty0 + y;
      const float lf = src[y * DIMX + xm];
      const float rt = src[y * DIMX + xp];
      const float4 vm = v[i + 1];
      const float4 va = (gy <= 0)       ? vm : v[i];      // replicate-pad top
      const float4 vb = (gy >= RES - 1) ? vm : v[i + 2];  // replicate-pad bottom
      const float n0 = va.x + vb.x + (lq0 ? vm.x : lf)   + (rq0 ? vm.x : vm.y);
      const float n1 = va.y + vb.y + (lq1 ? vm.y : vm.x) + (rq1 ? vm.y : vm.z);
      const float n2 = va.z + vb.z + (lq2 ? vm.z : vm.y) + (rq2 ? vm.z : vm.w);
      const float n3 = va.w + vb.w + (lq3 ? vm.w : vm.z) + (rq3 ? vm.w : rt);
      float4 nv;
      nv.x = fmaf(n0, Rq[i].x, Bq[i].x);
      nv.y = fmaf(n1, Rq[i].y, Bq[i].y);
      nv.z = fmaf(n2, Rq[i].z, Bq[i].z);
      nv.w = fmaf(n3, Rq[i].w, Bq[i].w);
      if (it < NITER) {
        *(float4*)(dst + y * DIMX + x0) = nv;
      } else {
        // final iteration: clamp epilogue straight from registers
        if (gy < RES) {
          const float o0 = (nv.x >= 1.0f) ? 0.95f : nv.x;
          const float o1 = (nv.y >= 1.0f) ? 0.95f : nv.y;
          const float o2 = (nv.z >= 1.0f) ? 0.95f : nv.z;
          const float o3 = (nv.w >= 1.0f) ? 0.95f : nv.w;
          const size_t ro = (size_t)gy * RES;
          if (fullq) {
            *(float2*)(OUT + ro + gx0)     = make_float2(o0, o1);
            *(float2*)(OUT + ro + gx0 + 2) = make_float2(o2, o3);
          } else {
            if (in0 && gx0 + 0 < RES) OUT[ro + gx0 + 0] = o0;
            if (in1 && gx0 + 1 < RES) OUT[ro + gx0 + 1] = o1;
            if (in2 && gx0 + 2 < RES) OUT[ro + gx0 + 2] = o2;
            if (in3 && gx0 + 3 < RES) OUT[ro + gx0 + 3] = o3;
          }
        }
      }
    }
    if (it < NITER) __syncthreads();
  }
}

extern "C" void kernel_launch(void* const* d_in, const int* in_sizes, int n_in,
                              void* d_out, int out_size, void* d_ws, size_t ws_size,
                              hipStream_t stream) {
  const float* Xin  = (const float*)d_in[0];
  const float* Cin  = (const float*)d_in[1];
  const int*   BT   = (const int*)d_in[2];
  const float* BCin = (const float*)d_in[3];
  float* OUT  = (float*)d_out;
  float* CPOS = OUT + (size_t)RES * RES;

  dim3 grid(NBX, NBY);
  dim3 block(256);
  hipLaunchKernelGGL(laplace10_fused, grid, block, 0, stream,
                     Xin, Cin, BT, BCin, OUT, CPOS);
}